// Round 1
// baseline (803.178 us; speedup 1.0000x reference)
//
#include <hip/hip_runtime.h>
#include <hip/hip_bf16.h>

typedef __attribute__((ext_vector_type(8))) __bf16 bf16x8;
typedef __attribute__((ext_vector_type(4))) float f32x4;
typedef __attribute__((ext_vector_type(4))) int i32x4;
typedef __attribute__((ext_vector_type(4))) unsigned short u16x4;

#define MFMA16(a, b, c) __builtin_amdgcn_mfma_f32_16x16x32_bf16((a), (b), (c), 0, 0, 0)

// ---------------------------------------------------------------- casts
// embedded (B,1024,1024) fp32 -> premise/hypothesis (8192,1024) bf16 contiguous
__global__ __launch_bounds__(256) void cast_emb_kernel(const float* __restrict__ emb,
                                                       __bf16* __restrict__ Pb,
                                                       __bf16* __restrict__ Hb)
{
    int i = (blockIdx.x * 256 + threadIdx.x) * 4;   // element in (8192,1024) dest space
    int r = i >> 10, d = i & 1023;
    size_t src = ((size_t)(r >> 9) * 1024 + (r & 511)) * 1024 + d;
    f32x4 p = *(const f32x4*)(emb + src);
    f32x4 h = *(const f32x4*)(emb + src + 512 * 1024);
    union { __bf16 b[4]; u16x4 u; } cp, ch;
#pragma unroll
    for (int j = 0; j < 4; ++j) { cp.b[j] = (__bf16)p[j]; ch.b[j] = (__bf16)h[j]; }
    *(u16x4*)(Pb + i) = cp.u;
    *(u16x4*)(Hb + i) = ch.u;
}

// W (1024,1024) fp32 row-major -> Wt (1024,1024) bf16, Wt[n][k] = W[k][n]
__global__ __launch_bounds__(256) void cast_wt_kernel(const float* __restrict__ W,
                                                      __bf16* __restrict__ Wt)
{
    __shared__ float tile[32][33];
    int n0 = blockIdx.x * 32, k0 = blockIdx.y * 32;
    int tx = threadIdx.x, ty = threadIdx.y;
#pragma unroll
    for (int i = ty; i < 32; i += 8)
        tile[i][tx] = W[(size_t)(k0 + i) * 1024 + n0 + tx];
    __syncthreads();
#pragma unroll
    for (int i = ty; i < 32; i += 8)
        Wt[(size_t)(n0 + i) * 1024 + k0 + tx] = (__bf16)tile[tx][i];
}

// ---------------------------------------------------------------- GEMM
// C(M,N) = A(M,K) @ Bt^T + bias.  A,Bt bf16 row-major, Bt is (N,K).
// EPI 0: Cb[row*N+col] = bf16(v)
// EPI 1: V-transpose write: Cb laid out (B,H,64,512):  [((b*16+h)*64+hd)*512 + pos]
// EPI 2: Cf[row*N+col] = v + resid  (fp32, resid = embedded slice)
template <int EPI>
__global__ __launch_bounds__(256, 2) void gemm_bt(const __bf16* __restrict__ A,
                                                  const __bf16* __restrict__ Bt,
                                                  const float* __restrict__ bias,
                                                  __bf16* __restrict__ Cb,
                                                  float* __restrict__ Cf,
                                                  const float* __restrict__ resid,
                                                  int resid_half, int M, int N, int K)
{
    __shared__ __align__(16) __bf16 As[128 * 32];
    __shared__ __align__(16) __bf16 Bs[128 * 32];
    const int t = threadIdx.x;
    const int l = t & 63, w = t >> 6;
    const int wr = w >> 1, wc = w & 1;
    const int lrow = l & 15, lk = l >> 4;
    const int m0 = blockIdx.y * 128, n0 = blockIdx.x * 128;
    const int r0 = t >> 2, kc0 = (t & 3) * 8;

    const __bf16* pA0 = A + (size_t)(m0 + r0) * K + kc0;
    const __bf16* pA1 = pA0 + (size_t)64 * K;
    const __bf16* pB0 = Bt + (size_t)(n0 + r0) * K + kc0;
    const __bf16* pB1 = pB0 + (size_t)64 * K;

    i32x4 ra0 = *(const i32x4*)pA0;
    i32x4 ra1 = *(const i32x4*)pA1;
    i32x4 rb0 = *(const i32x4*)pB0;
    i32x4 rb1 = *(const i32x4*)pB1;

    const f32x4 zero = {0.f, 0.f, 0.f, 0.f};
    f32x4 acc[4][4];
#pragma unroll
    for (int mi = 0; mi < 4; ++mi)
#pragma unroll
        for (int ni = 0; ni < 4; ++ni) acc[mi][ni] = zero;

    const int nk = K >> 5;
    for (int kt = 0; kt < nk; ++kt) {
        *(i32x4*)(&As[r0 * 32 + kc0]) = ra0;
        *(i32x4*)(&As[(r0 + 64) * 32 + kc0]) = ra1;
        *(i32x4*)(&Bs[r0 * 32 + kc0]) = rb0;
        *(i32x4*)(&Bs[(r0 + 64) * 32 + kc0]) = rb1;
        __syncthreads();
        if (kt + 1 < nk) {   // prefetch next K-tile into regs; overlaps MFMA below
            int ko = (kt + 1) * 32;
            ra0 = *(const i32x4*)(pA0 + ko);
            ra1 = *(const i32x4*)(pA1 + ko);
            rb0 = *(const i32x4*)(pB0 + ko);
            rb1 = *(const i32x4*)(pB1 + ko);
        }
        bf16x8 af[4], bfv[4];
#pragma unroll
        for (int mi = 0; mi < 4; ++mi)
            af[mi] = *(const bf16x8*)(&As[(wr * 64 + mi * 16 + lrow) * 32 + lk * 8]);
#pragma unroll
        for (int ni = 0; ni < 4; ++ni)
            bfv[ni] = *(const bf16x8*)(&Bs[(wc * 64 + ni * 16 + lrow) * 32 + lk * 8]);
#pragma unroll
        for (int mi = 0; mi < 4; ++mi)
#pragma unroll
            for (int ni = 0; ni < 4; ++ni)
                acc[mi][ni] = MFMA16(af[mi], bfv[ni], acc[mi][ni]);
        __syncthreads();
    }

#pragma unroll
    for (int mi = 0; mi < 4; ++mi) {
#pragma unroll
        for (int ni = 0; ni < 4; ++ni) {
            int col = n0 + wc * 64 + ni * 16 + lrow;
            float bv = bias[col];
#pragma unroll
            for (int r = 0; r < 4; ++r) {
                int row = m0 + wr * 64 + mi * 16 + lk * 4 + r;
                float v = acc[mi][ni][r] + bv;
                if (EPI == 0) {
                    Cb[(size_t)row * N + col] = (__bf16)v;
                } else if (EPI == 1) {
                    int b_ = row >> 9, pos = row & 511;
                    int h_ = col >> 6, hd = col & 63;
                    Cb[(((size_t)(b_ * 16 + h_) * 64 + hd) << 9) + pos] = (__bf16)v;
                } else {
                    int b_ = row >> 9, s = row & 511;
                    float rv = resid[((size_t)b_ * 1024 + resid_half + s) * 1024 + col];
                    Cf[(size_t)row * N + col] = v + rv;
                }
            }
        }
    }
}

// ---------------------------------------------------------------- attention
// One WG per (b,h, 64-row Q block). K and Vt fully staged in LDS; full-row softmax.
__global__ __launch_bounds__(256) void attn_kernel(const __bf16* __restrict__ Q,
                                                   const __bf16* __restrict__ Kb,
                                                   const __bf16* __restrict__ Vt,
                                                   const float* __restrict__ mask,
                                                   int mask_half,
                                                   __bf16* __restrict__ att)
{
    __shared__ __align__(16) __bf16 KP[512 * 64];  // K [pos][hd], later P [64 q][512 pos]
    __shared__ __align__(16) __bf16 Vs[64 * 512];  // Vt [hd][pos]
    __shared__ float msk[512];
    const int bh = blockIdx.y, b = bh >> 4, h = bh & 15;
    const int q0 = blockIdx.x * 64;
    const int t = threadIdx.x, l = t & 63, w = t >> 6;
    const int lrow = l & 15, lk = l >> 4;

#pragma unroll
    for (int i = 0; i < 16; ++i) {
        int c = t + i * 256;
        int pos = c >> 3, p8 = (c & 7) * 8;
        *(i32x4*)(&KP[pos * 64 + p8]) =
            *(const i32x4*)(&Kb[((size_t)(b * 512 + pos)) * 1024 + h * 64 + p8]);
    }
    const __bf16* vsrc = Vt + (size_t)bh * 64 * 512;
#pragma unroll
    for (int i = 0; i < 16; ++i) {
        int c = t + i * 256;
        *(i32x4*)(&Vs[c * 8]) = *(const i32x4*)(&vsrc[c * 8]);
    }
    for (int i = t; i < 512; i += 256) msk[i] = mask[b * 1024 + mask_half + i];

    // Q fragments (16 rows per wave)
    const int qrow = q0 + w * 16 + lrow;
    const __bf16* qptr = Q + ((size_t)(b * 512 + qrow)) * 1024 + h * 64;
    bf16x8 qf0 = *(const bf16x8*)(qptr + lk * 8);
    bf16x8 qf1 = *(const bf16x8*)(qptr + 32 + lk * 8);
    __syncthreads();

    const f32x4 zero = {0.f, 0.f, 0.f, 0.f};
    f32x4 sc[32];
#pragma unroll
    for (int j = 0; j < 32; ++j) {
        const __bf16* kb = &KP[(j * 16 + lrow) * 64];
        bf16x8 k0 = *(const bf16x8*)(kb + lk * 8);
        bf16x8 k1 = *(const bf16x8*)(kb + 32 + lk * 8);
        f32x4 c = zero;
        c = MFMA16(qf0, k0, c);
        c = MFMA16(qf1, k1, c);
        sc[j] = c;
    }

    // softmax: lane owns col j*16+lrow, rows lk*4+r
    float mx[4] = {-3e38f, -3e38f, -3e38f, -3e38f};
#pragma unroll
    for (int j = 0; j < 32; ++j) {
        float mv = msk[j * 16 + lrow];
#pragma unroll
        for (int r = 0; r < 4; ++r) {
            float s = sc[j][r] * 0.125f;      // 1/sqrt(64)
            if (mv == 0.f) s = -1e9f;
            sc[j][r] = s;
            mx[r] = fmaxf(mx[r], s);
        }
    }
#pragma unroll
    for (int r = 0; r < 4; ++r)
        for (int d = 1; d < 16; d <<= 1) mx[r] = fmaxf(mx[r], __shfl_xor(mx[r], d));
    float sm[4] = {0.f, 0.f, 0.f, 0.f};
#pragma unroll
    for (int j = 0; j < 32; ++j)
#pragma unroll
        for (int r = 0; r < 4; ++r) {
            float e = __expf(sc[j][r] - mx[r]);
            sc[j][r] = e;
            sm[r] += e;
        }
#pragma unroll
    for (int r = 0; r < 4; ++r)
        for (int d = 1; d < 16; d <<= 1) sm[r] += __shfl_xor(sm[r], d);
    float inv[4];
#pragma unroll
    for (int r = 0; r < 4; ++r) inv[r] = 1.f / sm[r];

    __syncthreads();   // all waves done reading K -> reuse KP for P
    __bf16* P = KP;    // [64][512], unnormalized exp
#pragma unroll
    for (int j = 0; j < 32; ++j)
#pragma unroll
        for (int r = 0; r < 4; ++r)
            P[(w * 16 + lk * 4 + r) * 512 + j * 16 + lrow] = (__bf16)sc[j][r];
    __syncthreads();

    f32x4 av[4];
#pragma unroll
    for (int ni = 0; ni < 4; ++ni) av[ni] = zero;
#pragma unroll
    for (int ks = 0; ks < 16; ++ks) {
        bf16x8 pf = *(const bf16x8*)(&P[(w * 16 + lrow) * 512 + ks * 32 + lk * 8]);
#pragma unroll
        for (int ni = 0; ni < 4; ++ni) {
            bf16x8 vf = *(const bf16x8*)(&Vs[(ni * 16 + lrow) * 512 + ks * 32 + lk * 8]);
            av[ni] = MFMA16(pf, vf, av[ni]);
        }
    }
#pragma unroll
    for (int ni = 0; ni < 4; ++ni)
#pragma unroll
        for (int r = 0; r < 4; ++r) {
            int qq = q0 + w * 16 + lk * 4 + r;
            att[((size_t)(b * 512 + qq)) * 1024 + h * 64 + ni * 16 + lrow] =
                (__bf16)(av[ni][r] * inv[r]);
        }
}

// ---------------------------------------------------------------- layernorm (row of 1024)
__global__ __launch_bounds__(256) void ln_kernel(const float* __restrict__ X,
                                                 const float* __restrict__ g,
                                                 const float* __restrict__ bta,
                                                 __bf16* __restrict__ out)
{
    const int r = blockIdx.x, t = threadIdx.x;
    const float* x = X + (size_t)r * 1024;
    f32x4 v = *(const f32x4*)(x + t * 4);
    float s = v[0] + v[1] + v[2] + v[3];
    float q = v[0] * v[0] + v[1] * v[1] + v[2] * v[2] + v[3] * v[3];
#pragma unroll
    for (int d = 1; d < 64; d <<= 1) { s += __shfl_xor(s, d); q += __shfl_xor(q, d); }
    __shared__ float rs[4], rq[4];
    if ((t & 63) == 0) { rs[t >> 6] = s; rq[t >> 6] = q; }
    __syncthreads();
    s = rs[0] + rs[1] + rs[2] + rs[3];
    q = rq[0] + rq[1] + rq[2] + rq[3];
    float mu = s * (1.f / 1024.f);
    float var = q * (1.f / 1024.f) - mu * mu;
    float rstd = rsqrtf(var + 1e-5f);
#pragma unroll
    for (int j = 0; j < 4; ++j) {
        int c = t * 4 + j;
        out[(size_t)r * 1024 + c] = (__bf16)((v[j] - mu) * rstd * g[c] + bta[c]);
    }
}

// ---------------------------------------------------------------- pools
__global__ __launch_bounds__(256) void pool_emb_kernel(const float* __restrict__ emb,
                                                       const float* __restrict__ mask,
                                                       int half, float* __restrict__ feats,
                                                       int off)
{
    int b = blockIdx.y;
    int d = blockIdx.x * 256 + threadIdx.x;
    float acc = 0.f, ms = 0.f;
    for (int s = 0; s < 512; ++s) {
        float m = mask[b * 1024 + half + s];
        acc += emb[((size_t)b * 1024 + half + s) * 1024 + d] * m;
        ms += m;
    }
    feats[b * 4096 + off + d] = acc / fmaxf(ms, 1e-9f);
}

__global__ __launch_bounds__(256) void pool_ctx_kernel(const __bf16* __restrict__ ctx,
                                                       const float* __restrict__ mask,
                                                       int half, float* __restrict__ feats,
                                                       int off)
{
    int b = blockIdx.y;
    int d = blockIdx.x * 256 + threadIdx.x;
    float acc = 0.f, ms = 0.f;
    for (int s = 0; s < 512; ++s) {
        float m = mask[b * 1024 + half + s];
        acc += (float)ctx[((size_t)b * 512 + s) * 1024 + d] * m;
        ms += m;
    }
    feats[b * 4096 + off + d] = acc / fmaxf(ms, 1e-9f);
}

// ---------------------------------------------------------------- small fp32 MLP
__global__ __launch_bounds__(256) void mlp_fc_kernel(const float* __restrict__ in,
                                                     const float* __restrict__ W,
                                                     const float* __restrict__ bias,
                                                     float* __restrict__ out,
                                                     int IF, int OF, int relu)
{
    const int t = threadIdx.x;
    const int jt = t & 15, sl = t >> 4;
    const int col = blockIdx.x * 16 + jt;
    const int per = IF >> 4;
    float acc[16];
#pragma unroll
    for (int b = 0; b < 16; ++b) acc[b] = 0.f;
    for (int i = sl * per; i < (sl + 1) * per; ++i) {
        float wv = W[(size_t)i * OF + col];
#pragma unroll
        for (int b = 0; b < 16; ++b) acc[b] += in[b * IF + i] * wv;
    }
    __shared__ float red[16][16][16];   // [slice][b][jt]
#pragma unroll
    for (int b = 0; b < 16; ++b) red[sl][b][jt] = acc[b];
    __syncthreads();
    const int b = t >> 4;
    float sv = bias[col];
#pragma unroll
    for (int s2 = 0; s2 < 16; ++s2) sv += red[s2][b][jt];
    if (relu) sv = fmaxf(sv, 0.f);
    out[b * OF + col] = sv;
}

__global__ __launch_bounds__(64) void mlp3_kernel(const float* __restrict__ h2,
                                                  const float* __restrict__ W3,
                                                  const float* __restrict__ b3,
                                                  float* __restrict__ out)
{
    int b = blockIdx.x, t = threadIdx.x;
    float a0 = 0.f, a1 = 0.f, a2 = 0.f;
    for (int i = t; i < 512; i += 64) {
        float hv = h2[b * 512 + i];
        a0 += hv * W3[i * 3 + 0];
        a1 += hv * W3[i * 3 + 1];
        a2 += hv * W3[i * 3 + 2];
    }
#pragma unroll
    for (int d = 1; d < 64; d <<= 1) {
        a0 += __shfl_xor(a0, d);
        a1 += __shfl_xor(a1, d);
        a2 += __shfl_xor(a2, d);
    }
    if (t == 0) {
        out[b * 3 + 0] = a0 + b3[0];
        out[b * 3 + 1] = a1 + b3[1];
        out[b * 3 + 2] = a2 + b3[2];
    }
}

// ---------------------------------------------------------------- launch
extern "C" void kernel_launch(void* const* d_in, const int* in_sizes, int n_in,
                              void* d_out, int out_size, void* d_ws, size_t ws_size,
                              hipStream_t stream)
{
    const float* emb  = (const float*)d_in[0];
    const float* mask = (const float*)d_in[1];
    const float* W1 = (const float*)d_in[22];
    const float* b1 = (const float*)d_in[23];
    const float* W2 = (const float*)d_in[24];
    const float* b2 = (const float*)d_in[25];
    const float* W3 = (const float*)d_in[26];
    const float* b3 = (const float*)d_in[27];

    char* ws = (char*)d_ws;
    constexpr size_t MB = 1ull << 20;
    __bf16* Pb    = (__bf16*)(ws);                 // 16 MB (8192,1024) bf16
    __bf16* Hb    = (__bf16*)(ws + 16 * MB);       // 16 MB
    __bf16* Wt    = (__bf16*)(ws + 32 * MB);       // 16 MB: 8 x (1024,1024) bf16 W^T
    __bf16* Qb    = (__bf16*)(ws + 48 * MB);       // 16 MB
    __bf16* Kb    = (__bf16*)(ws + 64 * MB);       // 16 MB
    __bf16* Vt    = (__bf16*)(ws + 80 * MB);       // 16 MB (B,H,64,512)
    __bf16* attb  = (__bf16*)(ws + 96 * MB);       // 16 MB
    float*  Of    = (float*) (ws + 48 * MB);       // 32 MB, aliases Qb+Kb (dead by then)
    __bf16* ctx   = (__bf16*)(ws + 112 * MB);      // 16 MB
    float*  feats = (float*) (ws + 128 * MB);      // 256 KB (16,4096)
    float*  h1    = (float*) (ws + 128 * MB + 512 * 1024);  // 64 KB
    float*  h2    = (float*) (ws + 129 * MB);      // 32 KB

    cast_emb_kernel<<<8192, 256, 0, stream>>>(emb, Pb, Hb);
    const int widx[8] = {2, 4, 6, 8, 12, 14, 16, 18};   // p2h Wq,Wk,Wv,Wo then h2p
    for (int i = 0; i < 8; ++i)
        cast_wt_kernel<<<dim3(32, 32), dim3(32, 8), 0, stream>>>(
            (const float*)d_in[widx[i]], Wt + (size_t)i * 1024 * 1024);

    dim3 gg(8, 64);   // (N/128, M/128)
    for (int dir = 0; dir < 2; ++dir) {
        const __bf16* qin  = dir ? Hb : Pb;
        const __bf16* kvin = dir ? Pb : Hb;
        const int base = dir ? 12 : 2;
        const __bf16* wq = Wt + (size_t)(dir * 4 + 0) * 1048576;
        const __bf16* wk = Wt + (size_t)(dir * 4 + 1) * 1048576;
        const __bf16* wv = Wt + (size_t)(dir * 4 + 2) * 1048576;
        const __bf16* wo = Wt + (size_t)(dir * 4 + 3) * 1048576;
        const float* bq  = (const float*)d_in[base + 1];
        const float* bk  = (const float*)d_in[base + 3];
        const float* bv  = (const float*)d_in[base + 5];
        const float* bo  = (const float*)d_in[base + 7];
        const float* lng = (const float*)d_in[base + 8];
        const float* lnb = (const float*)d_in[base + 9];
        const int kvhalf  = dir ? 0 : 512;    // p2h attends hypothesis (mask half 512)
        const int reshalf = dir ? 512 : 0;    // residual = q_in slice of embedded

        gemm_bt<0><<<gg, 256, 0, stream>>>(qin,  wq, bq, Qb, nullptr, nullptr, 0, 8192, 1024, 1024);
        gemm_bt<0><<<gg, 256, 0, stream>>>(kvin, wk, bk, Kb, nullptr, nullptr, 0, 8192, 1024, 1024);
        gemm_bt<1><<<gg, 256, 0, stream>>>(kvin, wv, bv, Vt, nullptr, nullptr, 0, 8192, 1024, 1024);
        attn_kernel<<<dim3(8, 256), 256, 0, stream>>>(Qb, Kb, Vt, mask, kvhalf, attb);
        gemm_bt<2><<<gg, 256, 0, stream>>>(attb, wo, bo, nullptr, Of, emb, reshalf, 8192, 1024, 1024);
        ln_kernel<<<8192, 256, 0, stream>>>(Of, lng, lnb, ctx);
        pool_ctx_kernel<<<dim3(4, 16), 256, 0, stream>>>(ctx, mask, dir ? 512 : 0,
                                                         feats, 2048 + dir * 1024);
    }
    pool_emb_kernel<<<dim3(4, 16), 256, 0, stream>>>(emb, mask, 0,   feats, 0);
    pool_emb_kernel<<<dim3(4, 16), 256, 0, stream>>>(emb, mask, 512, feats, 1024);
    mlp_fc_kernel<<<64, 256, 0, stream>>>(feats, W1, b1, h1, 4096, 1024, 1);
    mlp_fc_kernel<<<32, 256, 0, stream>>>(h1, W2, b2, h2, 1024, 512, 1);
    mlp3_kernel<<<16, 64, 0, stream>>>(h2, W3, b3, (float*)d_out);
}

// Round 2
// 663.543 us; speedup vs baseline: 1.2104x; 1.2104x over previous
//
#include <hip/hip_runtime.h>
#include <hip/hip_bf16.h>

typedef __attribute__((ext_vector_type(8))) __bf16 bf16x8;
typedef __attribute__((ext_vector_type(4))) float f32x4;
typedef __attribute__((ext_vector_type(4))) int i32x4;
typedef __attribute__((ext_vector_type(4))) unsigned short u16x4;

#define MFMA16(a, b, c) __builtin_amdgcn_mfma_f32_16x16x32_bf16((a), (b), (c), 0, 0, 0)

// ---------------------------------------------------------------- casts
// embedded (B,1024,1024) fp32 -> premise/hypothesis (8192,1024) bf16 contiguous
__global__ __launch_bounds__(256) void cast_emb_kernel(const float* __restrict__ emb,
                                                       __bf16* __restrict__ Pb,
                                                       __bf16* __restrict__ Hb)
{
    int i = (blockIdx.x * 256 + threadIdx.x) * 4;   // element in (8192,1024) dest space
    int r = i >> 10, d = i & 1023;
    size_t src = ((size_t)(r >> 9) * 1024 + (r & 511)) * 1024 + d;
    f32x4 p = *(const f32x4*)(emb + src);
    f32x4 h = *(const f32x4*)(emb + src + 512 * 1024);
    union { __bf16 b[4]; u16x4 u; } cp, ch;
#pragma unroll
    for (int j = 0; j < 4; ++j) { cp.b[j] = (__bf16)p[j]; ch.b[j] = (__bf16)h[j]; }
    *(u16x4*)(Pb + i) = cp.u;
    *(u16x4*)(Hb + i) = ch.u;
}

// W (1024,1024) fp32 row-major -> Wt (1024,1024) bf16, Wt[n][k] = W[k][n]
__global__ __launch_bounds__(256) void cast_wt_kernel(const float* __restrict__ W,
                                                      __bf16* __restrict__ Wt)
{
    __shared__ float tile[32][33];
    int n0 = blockIdx.x * 32, k0 = blockIdx.y * 32;
    int tx = threadIdx.x, ty = threadIdx.y;
#pragma unroll
    for (int i = ty; i < 32; i += 8)
        tile[i][tx] = W[(size_t)(k0 + i) * 1024 + n0 + tx];
    __syncthreads();
#pragma unroll
    for (int i = ty; i < 32; i += 8)
        Wt[(size_t)(n0 + i) * 1024 + k0 + tx] = (__bf16)tile[tx][i];
}

// ---------------------------------------------------------------- GEMM
// C(M,N) = A(M,K) @ Bt^T + bias.  A,Bt bf16 row-major, Bt is (N,K).
// EPI 0: Cb[row*N+col] = bf16(v)
// EPI 1: V-transpose write: Cb laid out (B,H,64,512):  [((b*16+h)*64+hd)*512 + pos]
// EPI 2: Cf[row*N+col] = v + resid  (fp32, resid = embedded slice)
template <int EPI>
__global__ __launch_bounds__(256, 2) void gemm_bt(const __bf16* __restrict__ A,
                                                  const __bf16* __restrict__ Bt,
                                                  const float* __restrict__ bias,
                                                  __bf16* __restrict__ Cb,
                                                  float* __restrict__ Cf,
                                                  const float* __restrict__ resid,
                                                  int resid_half, int M, int N, int K)
{
    __shared__ __align__(16) __bf16 As[128 * 32];
    __shared__ __align__(16) __bf16 Bs[128 * 32];
    const int t = threadIdx.x;
    const int l = t & 63, w = t >> 6;
    const int wr = w >> 1, wc = w & 1;
    const int lrow = l & 15, lk = l >> 4;
    const int m0 = blockIdx.y * 128, n0 = blockIdx.x * 128;
    const int r0 = t >> 2, kc0 = (t & 3) * 8;

    const __bf16* pA0 = A + (size_t)(m0 + r0) * K + kc0;
    const __bf16* pA1 = pA0 + (size_t)64 * K;
    const __bf16* pB0 = Bt + (size_t)(n0 + r0) * K + kc0;
    const __bf16* pB1 = pB0 + (size_t)64 * K;

    i32x4 ra0 = *(const i32x4*)pA0;
    i32x4 ra1 = *(const i32x4*)pA1;
    i32x4 rb0 = *(const i32x4*)pB0;
    i32x4 rb1 = *(const i32x4*)pB1;

    const f32x4 zero = {0.f, 0.f, 0.f, 0.f};
    f32x4 acc[4][4];
#pragma unroll
    for (int mi = 0; mi < 4; ++mi)
#pragma unroll
        for (int ni = 0; ni < 4; ++ni) acc[mi][ni] = zero;

    const int nk = K >> 5;
    for (int kt = 0; kt < nk; ++kt) {
        *(i32x4*)(&As[r0 * 32 + kc0]) = ra0;
        *(i32x4*)(&As[(r0 + 64) * 32 + kc0]) = ra1;
        *(i32x4*)(&Bs[r0 * 32 + kc0]) = rb0;
        *(i32x4*)(&Bs[(r0 + 64) * 32 + kc0]) = rb1;
        __syncthreads();
        if (kt + 1 < nk) {   // prefetch next K-tile into regs; overlaps MFMA below
            int ko = (kt + 1) * 32;
            ra0 = *(const i32x4*)(pA0 + ko);
            ra1 = *(const i32x4*)(pA1 + ko);
            rb0 = *(const i32x4*)(pB0 + ko);
            rb1 = *(const i32x4*)(pB1 + ko);
        }
        bf16x8 af[4], bfv[4];
#pragma unroll
        for (int mi = 0; mi < 4; ++mi)
            af[mi] = *(const bf16x8*)(&As[(wr * 64 + mi * 16 + lrow) * 32 + lk * 8]);
#pragma unroll
        for (int ni = 0; ni < 4; ++ni)
            bfv[ni] = *(const bf16x8*)(&Bs[(wc * 64 + ni * 16 + lrow) * 32 + lk * 8]);
#pragma unroll
        for (int mi = 0; mi < 4; ++mi)
#pragma unroll
            for (int ni = 0; ni < 4; ++ni)
                acc[mi][ni] = MFMA16(af[mi], bfv[ni], acc[mi][ni]);
        __syncthreads();
    }

#pragma unroll
    for (int mi = 0; mi < 4; ++mi) {
#pragma unroll
        for (int ni = 0; ni < 4; ++ni) {
            int col = n0 + wc * 64 + ni * 16 + lrow;
            float bv = bias[col];
#pragma unroll
            for (int r = 0; r < 4; ++r) {
                int row = m0 + wr * 64 + mi * 16 + lk * 4 + r;
                float v = acc[mi][ni][r] + bv;
                if (EPI == 0) {
                    Cb[(size_t)row * N + col] = (__bf16)v;
                } else if (EPI == 1) {
                    int b_ = row >> 9, pos = row & 511;
                    int h_ = col >> 6, hd = col & 63;
                    Cb[(((size_t)(b_ * 16 + h_) * 64 + hd) << 9) + pos] = (__bf16)v;
                } else {
                    int b_ = row >> 9, s = row & 511;
                    float rv = resid[((size_t)b_ * 1024 + resid_half + s) * 1024 + col];
                    Cf[(size_t)row * N + col] = v + rv;
                }
            }
        }
    }
}

// ---------------------------------------------------------------- attention
// One WG per (b,h, 64-row Q block). K and Vt fully staged in LDS; full-row softmax.
__global__ __launch_bounds__(256) void attn_kernel(const __bf16* __restrict__ Q,
                                                   const __bf16* __restrict__ Kb,
                                                   const __bf16* __restrict__ Vt,
                                                   const float* __restrict__ mask,
                                                   int mask_half,
                                                   __bf16* __restrict__ att)
{
    __shared__ __align__(16) __bf16 KP[512 * 64];  // K [pos][hd], later P [64 q][512 pos]
    __shared__ __align__(16) __bf16 Vs[64 * 512];  // Vt [hd][pos]
    __shared__ float msk[512];
    const int bh = blockIdx.y, b = bh >> 4, h = bh & 15;
    const int q0 = blockIdx.x * 64;
    const int t = threadIdx.x, l = t & 63, w = t >> 6;
    const int lrow = l & 15, lk = l >> 4;

#pragma unroll
    for (int i = 0; i < 16; ++i) {
        int c = t + i * 256;
        int pos = c >> 3, p8 = (c & 7) * 8;
        *(i32x4*)(&KP[pos * 64 + p8]) =
            *(const i32x4*)(&Kb[((size_t)(b * 512 + pos)) * 1024 + h * 64 + p8]);
    }
    const __bf16* vsrc = Vt + (size_t)bh * 64 * 512;
#pragma unroll
    for (int i = 0; i < 16; ++i) {
        int c = t + i * 256;
        *(i32x4*)(&Vs[c * 8]) = *(const i32x4*)(&vsrc[c * 8]);
    }
    for (int i = t; i < 512; i += 256) msk[i] = mask[b * 1024 + mask_half + i];

    // Q fragments (16 rows per wave)
    const int qrow = q0 + w * 16 + lrow;
    const __bf16* qptr = Q + ((size_t)(b * 512 + qrow)) * 1024 + h * 64;
    bf16x8 qf0 = *(const bf16x8*)(qptr + lk * 8);
    bf16x8 qf1 = *(const bf16x8*)(qptr + 32 + lk * 8);
    __syncthreads();

    const f32x4 zero = {0.f, 0.f, 0.f, 0.f};
    f32x4 sc[32];
#pragma unroll
    for (int j = 0; j < 32; ++j) {
        const __bf16* kb = &KP[(j * 16 + lrow) * 64];
        bf16x8 k0 = *(const bf16x8*)(kb + lk * 8);
        bf16x8 k1 = *(const bf16x8*)(kb + 32 + lk * 8);
        f32x4 c = zero;
        c = MFMA16(qf0, k0, c);
        c = MFMA16(qf1, k1, c);
        sc[j] = c;
    }

    // softmax: lane owns col j*16+lrow, rows lk*4+r
    float mx[4] = {-3e38f, -3e38f, -3e38f, -3e38f};
#pragma unroll
    for (int j = 0; j < 32; ++j) {
        float mv = msk[j * 16 + lrow];
#pragma unroll
        for (int r = 0; r < 4; ++r) {
            float s = sc[j][r] * 0.125f;      // 1/sqrt(64)
            if (mv == 0.f) s = -1e9f;
            sc[j][r] = s;
            mx[r] = fmaxf(mx[r], s);
        }
    }
#pragma unroll
    for (int r = 0; r < 4; ++r)
        for (int d = 1; d < 16; d <<= 1) mx[r] = fmaxf(mx[r], __shfl_xor(mx[r], d));
    float sm[4] = {0.f, 0.f, 0.f, 0.f};
#pragma unroll
    for (int j = 0; j < 32; ++j)
#pragma unroll
        for (int r = 0; r < 4; ++r) {
            float e = __expf(sc[j][r] - mx[r]);
            sc[j][r] = e;
            sm[r] += e;
        }
#pragma unroll
    for (int r = 0; r < 4; ++r)
        for (int d = 1; d < 16; d <<= 1) sm[r] += __shfl_xor(sm[r], d);
    float inv[4];
#pragma unroll
    for (int r = 0; r < 4; ++r) inv[r] = 1.f / sm[r];

    __syncthreads();   // all waves done reading K -> reuse KP for P
    __bf16* P = KP;    // [64][512], unnormalized exp
#pragma unroll
    for (int j = 0; j < 32; ++j)
#pragma unroll
        for (int r = 0; r < 4; ++r)
            P[(w * 16 + lk * 4 + r) * 512 + j * 16 + lrow] = (__bf16)sc[j][r];
    __syncthreads();

    f32x4 av[4];
#pragma unroll
    for (int ni = 0; ni < 4; ++ni) av[ni] = zero;
#pragma unroll
    for (int ks = 0; ks < 16; ++ks) {
        bf16x8 pf = *(const bf16x8*)(&P[(w * 16 + lrow) * 512 + ks * 32 + lk * 8]);
#pragma unroll
        for (int ni = 0; ni < 4; ++ni) {
            bf16x8 vf = *(const bf16x8*)(&Vs[(ni * 16 + lrow) * 512 + ks * 32 + lk * 8]);
            av[ni] = MFMA16(pf, vf, av[ni]);
        }
    }
#pragma unroll
    for (int ni = 0; ni < 4; ++ni)
#pragma unroll
        for (int r = 0; r < 4; ++r) {
            int qq = q0 + w * 16 + lk * 4 + r;
            att[((size_t)(b * 512 + qq)) * 1024 + h * 64 + ni * 16 + lrow] =
                (__bf16)(av[ni][r] * inv[r]);
        }
}

// ---------------------------------------------------------------- layernorm (row of 1024)
__global__ __launch_bounds__(256) void ln_kernel(const float* __restrict__ X,
                                                 const float* __restrict__ g,
                                                 const float* __restrict__ bta,
                                                 __bf16* __restrict__ out)
{
    const int r = blockIdx.x, t = threadIdx.x;
    const float* x = X + (size_t)r * 1024;
    f32x4 v = *(const f32x4*)(x + t * 4);
    float s = v[0] + v[1] + v[2] + v[3];
    float q = v[0] * v[0] + v[1] * v[1] + v[2] * v[2] + v[3] * v[3];
#pragma unroll
    for (int d = 1; d < 64; d <<= 1) { s += __shfl_xor(s, d); q += __shfl_xor(q, d); }
    __shared__ float rs[4], rq[4];
    if ((t & 63) == 0) { rs[t >> 6] = s; rq[t >> 6] = q; }
    __syncthreads();
    s = rs[0] + rs[1] + rs[2] + rs[3];
    q = rq[0] + rq[1] + rq[2] + rq[3];
    float mu = s * (1.f / 1024.f);
    float var = q * (1.f / 1024.f) - mu * mu;
    float rstd = rsqrtf(var + 1e-5f);
#pragma unroll
    for (int j = 0; j < 4; ++j) {
        int c = t * 4 + j;
        out[(size_t)r * 1024 + c] = (__bf16)((v[j] - mu) * rstd * g[c] + bta[c]);
    }
}

// ---------------------------------------------------------------- pools
// X = embedded (16,1024,1024) fp32; pool rows [half, half+512) -> feats[b][off+d]
// grid (16 d-tiles of 64, 16 b); 4 waves split S into 4 slices of 128.
__global__ __launch_bounds__(256) void pool_f32_kernel(const float* __restrict__ X,
                                                       const float* __restrict__ mask,
                                                       int half, float* __restrict__ feats,
                                                       int off)
{
    const int b = blockIdx.y, d0 = blockIdx.x * 64;
    const int t = threadIdx.x, d = d0 + (t & 63), sl = t >> 6;
    float acc = 0.f, ms = 0.f;
#pragma unroll 4
    for (int s = sl * 128; s < sl * 128 + 128; ++s) {
        float m = mask[b * 1024 + half + s];
        acc += X[((size_t)b * 1024 + half + s) * 1024 + d] * m;
        ms += m;
    }
    __shared__ float ra[4][64];
    __shared__ float rm[4];
    ra[sl][t & 63] = acc;
    if ((t & 63) == 0) rm[sl] = ms;
    __syncthreads();
    if (t < 64) {
        float a = ra[0][t] + ra[1][t] + ra[2][t] + ra[3][t];
        float m = rm[0] + rm[1] + rm[2] + rm[3];
        feats[b * 4096 + off + d0 + t] = a / fmaxf(m, 1e-9f);
    }
}

// X = ctx (16*512,1024) bf16 (row = b*512+s); same pooling
__global__ __launch_bounds__(256) void pool_bf16_kernel(const __bf16* __restrict__ X,
                                                        const float* __restrict__ mask,
                                                        int half, float* __restrict__ feats,
                                                        int off)
{
    const int b = blockIdx.y, d0 = blockIdx.x * 64;
    const int t = threadIdx.x, d = d0 + (t & 63), sl = t >> 6;
    float acc = 0.f, ms = 0.f;
#pragma unroll 4
    for (int s = sl * 128; s < sl * 128 + 128; ++s) {
        float m = mask[b * 1024 + half + s];
        acc += (float)X[((size_t)b * 512 + s) * 1024 + d] * m;
        ms += m;
    }
    __shared__ float ra[4][64];
    __shared__ float rm[4];
    ra[sl][t & 63] = acc;
    if ((t & 63) == 0) rm[sl] = ms;
    __syncthreads();
    if (t < 64) {
        float a = ra[0][t] + ra[1][t] + ra[2][t] + ra[3][t];
        float m = rm[0] + rm[1] + rm[2] + rm[3];
        feats[b * 4096 + off + d0 + t] = a / fmaxf(m, 1e-9f);
    }
}

// ---------------------------------------------------------------- small fp32 MLP
// h1pre (16,1024) <- b1 ; h2pre (16,512) <- b2
__global__ __launch_bounds__(256) void fc_init_kernel(const float* __restrict__ b1,
                                                      const float* __restrict__ b2,
                                                      float* __restrict__ h1,
                                                      float* __restrict__ h2)
{
    int i = blockIdx.x * 256 + threadIdx.x;
    if (i < 16 * 1024) h1[i] = b1[i & 1023];
    else h2[i - 16 * 1024] = b2[(i - 16 * 1024) & 511];
}

// out[b][col] += sum_{i in chunk} relu?(in[b][i]) * W[i][col]
// grid (OF/256, IF/CH); 256 threads = 256 cols.
template <int CH, int RELU_IN>
__global__ __launch_bounds__(256) void fc_atomic_kernel(const float* __restrict__ in,
                                                        const float* __restrict__ W,
                                                        float* __restrict__ out,
                                                        int IF, int OF)
{
    __shared__ float ins[16 * CH];
    const int t = threadIdx.x;
    const int col = blockIdx.x * 256 + t;
    const int i0 = blockIdx.y * CH;
#pragma unroll
    for (int idx = t; idx < 16 * CH; idx += 256) {
        int b = idx / CH, i = idx % CH;
        float v = in[b * IF + i0 + i];
        if (RELU_IN) v = fmaxf(v, 0.f);
        ins[idx] = v;
    }
    __syncthreads();
    float acc[16];
#pragma unroll
    for (int b = 0; b < 16; ++b) acc[b] = 0.f;
#pragma unroll 4
    for (int i = 0; i < CH; ++i) {
        float wv = W[(size_t)(i0 + i) * OF + col];
#pragma unroll
        for (int b = 0; b < 16; ++b) acc[b] += ins[b * CH + i] * wv;
    }
#pragma unroll
    for (int b = 0; b < 16; ++b) atomicAdd(out + b * OF + col, acc[b]);
}

__global__ __launch_bounds__(64) void mlp3_kernel(const float* __restrict__ h2,
                                                  const float* __restrict__ W3,
                                                  const float* __restrict__ b3,
                                                  float* __restrict__ out)
{
    int b = blockIdx.x, t = threadIdx.x;
    float a0 = 0.f, a1 = 0.f, a2 = 0.f;
    for (int i = t; i < 512; i += 64) {
        float hv = fmaxf(h2[b * 512 + i], 0.f);
        a0 += hv * W3[i * 3 + 0];
        a1 += hv * W3[i * 3 + 1];
        a2 += hv * W3[i * 3 + 2];
    }
#pragma unroll
    for (int d = 1; d < 64; d <<= 1) {
        a0 += __shfl_xor(a0, d);
        a1 += __shfl_xor(a1, d);
        a2 += __shfl_xor(a2, d);
    }
    if (t == 0) {
        out[b * 3 + 0] = a0 + b3[0];
        out[b * 3 + 1] = a1 + b3[1];
        out[b * 3 + 2] = a2 + b3[2];
    }
}

// ---------------------------------------------------------------- launch
extern "C" void kernel_launch(void* const* d_in, const int* in_sizes, int n_in,
                              void* d_out, int out_size, void* d_ws, size_t ws_size,
                              hipStream_t stream)
{
    const float* emb  = (const float*)d_in[0];
    const float* mask = (const float*)d_in[1];
    const float* W1 = (const float*)d_in[22];
    const float* b1 = (const float*)d_in[23];
    const float* W2 = (const float*)d_in[24];
    const float* b2 = (const float*)d_in[25];
    const float* W3 = (const float*)d_in[26];
    const float* b3 = (const float*)d_in[27];

    char* ws = (char*)d_ws;
    constexpr size_t MB = 1ull << 20;
    __bf16* Pb    = (__bf16*)(ws);                 // 16 MB (8192,1024) bf16
    __bf16* Hb    = (__bf16*)(ws + 16 * MB);       // 16 MB
    __bf16* Wt    = (__bf16*)(ws + 32 * MB);       // 16 MB: 8 x (1024,1024) bf16 W^T
    __bf16* Qb    = (__bf16*)(ws + 48 * MB);       // 16 MB
    __bf16* Kb    = (__bf16*)(ws + 64 * MB);       // 16 MB
    __bf16* Vt    = (__bf16*)(ws + 80 * MB);       // 16 MB (B,H,64,512)
    __bf16* attb  = (__bf16*)(ws + 96 * MB);       // 16 MB
    float*  Of    = (float*) (ws + 48 * MB);       // 32 MB, aliases Qb+Kb (dead by then)
    __bf16* ctx   = (__bf16*)(ws + 112 * MB);      // 16 MB
    float*  feats = (float*) (ws + 128 * MB);      // 256 KB (16,4096)
    float*  h1    = (float*) (ws + 128 * MB + 512 * 1024);  // 64 KB
    float*  h2    = (float*) (ws + 129 * MB);      // 32 KB

    cast_emb_kernel<<<8192, 256, 0, stream>>>(emb, Pb, Hb);
    const int widx[8] = {2, 4, 6, 8, 12, 14, 16, 18};   // p2h Wq,Wk,Wv,Wo then h2p
    for (int i = 0; i < 8; ++i)
        cast_wt_kernel<<<dim3(32, 32), dim3(32, 8), 0, stream>>>(
            (const float*)d_in[widx[i]], Wt + (size_t)i * 1024 * 1024);

    dim3 gg(8, 64);   // (N/128, M/128)
    for (int dir = 0; dir < 2; ++dir) {
        const __bf16* qin  = dir ? Hb : Pb;
        const __bf16* kvin = dir ? Pb : Hb;
        const int base = dir ? 12 : 2;
        const __bf16* wq = Wt + (size_t)(dir * 4 + 0) * 1048576;
        const __bf16* wk = Wt + (size_t)(dir * 4 + 1) * 1048576;
        const __bf16* wv = Wt + (size_t)(dir * 4 + 2) * 1048576;
        const __bf16* wo = Wt + (size_t)(dir * 4 + 3) * 1048576;
        const float* bq  = (const float*)d_in[base + 1];
        const float* bk  = (const float*)d_in[base + 3];
        const float* bv  = (const float*)d_in[base + 5];
        const float* bo  = (const float*)d_in[base + 7];
        const float* lng = (const float*)d_in[base + 8];
        const float* lnb = (const float*)d_in[base + 9];
        const int kvhalf  = dir ? 0 : 512;    // p2h attends hypothesis (mask half 512)
        const int reshalf = dir ? 512 : 0;    // residual = q_in slice of embedded

        gemm_bt<0><<<gg, 256, 0, stream>>>(qin,  wq, bq, Qb, nullptr, nullptr, 0, 8192, 1024, 1024);
        gemm_bt<0><<<gg, 256, 0, stream>>>(kvin, wk, bk, Kb, nullptr, nullptr, 0, 8192, 1024, 1024);
        gemm_bt<1><<<gg, 256, 0, stream>>>(kvin, wv, bv, Vt, nullptr, nullptr, 0, 8192, 1024, 1024);
        attn_kernel<<<dim3(8, 256), 256, 0, stream>>>(Qb, Kb, Vt, mask, kvhalf, attb);
        gemm_bt<2><<<gg, 256, 0, stream>>>(attb, wo, bo, nullptr, Of, emb, reshalf, 8192, 1024, 1024);
        ln_kernel<<<8192, 256, 0, stream>>>(Of, lng, lnb, ctx);
        pool_bf16_kernel<<<dim3(16, 16), 256, 0, stream>>>(ctx, mask, dir ? 512 : 0,
                                                           feats, 2048 + dir * 1024);
    }
    pool_f32_kernel<<<dim3(16, 16), 256, 0, stream>>>(emb, mask, 0,   feats, 0);
    pool_f32_kernel<<<dim3(16, 16), 256, 0, stream>>>(emb, mask, 512, feats, 1024);

    fc_init_kernel<<<96, 256, 0, stream>>>(b1, b2, h1, h2);
    fc_atomic_kernel<128, 0><<<dim3(4, 32), 256, 0, stream>>>(feats, W1, h1, 4096, 1024);
    fc_atomic_kernel<32, 1><<<dim3(2, 32), 256, 0, stream>>>(h1, W2, h2, 1024, 512);
    mlp3_kernel<<<16, 64, 0, stream>>>(h2, W3, b3, (float*)d_out);
}

// Round 3
// 623.325 us; speedup vs baseline: 1.2885x; 1.0645x over previous
//
#include <hip/hip_runtime.h>
#include <hip/hip_bf16.h>

typedef __attribute__((ext_vector_type(8))) __bf16 bf16x8;
typedef __attribute__((ext_vector_type(4))) float f32x4;
typedef __attribute__((ext_vector_type(4))) int i32x4;
typedef __attribute__((ext_vector_type(4))) unsigned short u16x4;

#define MFMA16(a, b, c) __builtin_amdgcn_mfma_f32_16x16x32_bf16((a), (b), (c), 0, 0, 0)

__device__ __forceinline__ void gload_lds16(const void* g, void* l)
{
    __builtin_amdgcn_global_load_lds(
        (const __attribute__((address_space(1))) unsigned int*)g,
        (__attribute__((address_space(3))) unsigned int*)l, 16, 0, 0);
}

// ---------------------------------------------------------------- casts
// embedded (B,1024,1024) fp32 -> premise/hypothesis (8192,1024) bf16 contiguous
__global__ __launch_bounds__(256) void cast_emb_kernel(const float* __restrict__ emb,
                                                       __bf16* __restrict__ Pb,
                                                       __bf16* __restrict__ Hb)
{
    int i = (blockIdx.x * 256 + threadIdx.x) * 4;   // element in (8192,1024) dest space
    int r = i >> 10, d = i & 1023;
    size_t src = ((size_t)(r >> 9) * 1024 + (r & 511)) * 1024 + d;
    f32x4 p = *(const f32x4*)(emb + src);
    f32x4 h = *(const f32x4*)(emb + src + 512 * 1024);
    union { __bf16 b[4]; u16x4 u; } cp, ch;
#pragma unroll
    for (int j = 0; j < 4; ++j) { cp.b[j] = (__bf16)p[j]; ch.b[j] = (__bf16)h[j]; }
    *(u16x4*)(Pb + i) = cp.u;
    *(u16x4*)(Hb + i) = ch.u;
}

// W (1024,1024) fp32 row-major -> Wt (1024,1024) bf16, Wt[n][k] = W[k][n]
__global__ __launch_bounds__(256) void cast_wt_kernel(const float* __restrict__ W,
                                                      __bf16* __restrict__ Wt)
{
    __shared__ float tile[32][33];
    int n0 = blockIdx.x * 32, k0 = blockIdx.y * 32;
    int tx = threadIdx.x, ty = threadIdx.y;
#pragma unroll
    for (int i = ty; i < 32; i += 8)
        tile[i][tx] = W[(size_t)(k0 + i) * 1024 + n0 + tx];
    __syncthreads();
#pragma unroll
    for (int i = ty; i < 32; i += 8)
        Wt[(size_t)(n0 + i) * 1024 + k0 + tx] = (__bf16)tile[tx][i];
}

// ---------------------------------------------------------------- GEMM (m97 structure)
// C(M,N) = A(M,K) @ Bt^T + bias.  A,Bt bf16 row-major, Bt is (N,K).
// EPI 0: Cb[row*N+col] = bf16(v)
// EPI 1: V-transpose write: Cb laid out (B,H,64,512):  [((b*16+h)*64+hd)*512 + pos]
// EPI 2: Cf[row*N+col] = v + resid  (fp32, resid = embedded slice)
template <int EPI>
__global__ __launch_bounds__(256, 3) void gemm_bt(const __bf16* __restrict__ A,
                                                  const __bf16* __restrict__ Bt,
                                                  const float* __restrict__ bias,
                                                  __bf16* __restrict__ Cb,
                                                  float* __restrict__ Cf,
                                                  const float* __restrict__ resid,
                                                  int resid_half, int M, int N, int K)
{
    __shared__ __align__(16) __bf16 As[128 * 32];
    __shared__ __align__(16) __bf16 Bs[128 * 32];
    const int t = threadIdx.x;
    const int l = t & 63, w = t >> 6;
    const int wr = w >> 1, wc = w & 1;
    const int lrow = l & 15, lk = l >> 4;
    const int m0 = blockIdx.y * 128, n0 = blockIdx.x * 128;
    const int r0 = t >> 2, kc0 = (t & 3) * 8;

    const __bf16* gA0 = A + (size_t)(m0 + r0) * K + kc0;
    const __bf16* gA1 = gA0 + (size_t)64 * K;
    const __bf16* gB0 = Bt + (size_t)(n0 + r0) * K + kc0;
    const __bf16* gB1 = gB0 + (size_t)64 * K;
    // LDS dests are lane-linear (byte offset == t*16) -> valid global_load_lds targets
    __bf16* dA0 = &As[r0 * 32 + kc0];
    __bf16* dA1 = &As[(r0 + 64) * 32 + kc0];
    __bf16* dB0 = &Bs[r0 * 32 + kc0];
    __bf16* dB1 = &Bs[(r0 + 64) * 32 + kc0];

    const f32x4 zero = {0.f, 0.f, 0.f, 0.f};
    f32x4 acc[4][4];
#pragma unroll
    for (int mi = 0; mi < 4; ++mi)
#pragma unroll
        for (int ni = 0; ni < 4; ++ni) acc[mi][ni] = zero;

    const int nk = K >> 5;
    for (int kt = 0; kt < nk; ++kt) {
        const int ko = kt * 32;
        gload_lds16(gA0 + ko, dA0);
        gload_lds16(gA1 + ko, dA1);
        gload_lds16(gB0 + ko, dB0);
        gload_lds16(gB1 + ko, dB1);
        __syncthreads();   // compiler emits vmcnt(0) drain before barrier -> LDS ready
        bf16x8 af[4], bfv[4];
#pragma unroll
        for (int mi = 0; mi < 4; ++mi)
            af[mi] = *(const bf16x8*)(&As[(wr * 64 + mi * 16 + lrow) * 32 + lk * 8]);
#pragma unroll
        for (int ni = 0; ni < 4; ++ni)
            bfv[ni] = *(const bf16x8*)(&Bs[(wc * 64 + ni * 16 + lrow) * 32 + lk * 8]);
#pragma unroll
        for (int mi = 0; mi < 4; ++mi)
#pragma unroll
            for (int ni = 0; ni < 4; ++ni)
                acc[mi][ni] = MFMA16(af[mi], bfv[ni], acc[mi][ni]);
        __syncthreads();
    }

#pragma unroll
    for (int mi = 0; mi < 4; ++mi) {
#pragma unroll
        for (int ni = 0; ni < 4; ++ni) {
            int col = n0 + wc * 64 + ni * 16 + lrow;
            float bv = bias[col];
#pragma unroll
            for (int r = 0; r < 4; ++r) {
                int row = m0 + wr * 64 + mi * 16 + lk * 4 + r;
                float v = acc[mi][ni][r] + bv;
                if (EPI == 0) {
                    Cb[(size_t)row * N + col] = (__bf16)v;
                } else if (EPI == 1) {
                    int b_ = row >> 9, pos = row & 511;
                    int h_ = col >> 6, hd = col & 63;
                    Cb[(((size_t)(b_ * 16 + h_) * 64 + hd) << 9) + pos] = (__bf16)v;
                } else {
                    int b_ = row >> 9, s = row & 511;
                    float rv = resid[((size_t)b_ * 1024 + resid_half + s) * 1024 + col];
                    Cf[(size_t)row * N + col] = v + rv;
                }
            }
        }
    }
}

// ---------------------------------------------------------------- attention
// One WG per (bh, 64-row Q block). K staged swizzled in LDS (reused as P);
// V read directly from global (L2-resident, 8 WGs/bh reuse).
// grid (256 bh, 8 qblk): linear id % 8 == bh % 8 -> same-bh WGs share an XCD L2.
__global__ __launch_bounds__(256, 2) void attn_kernel(const __bf16* __restrict__ Q,
                                                      const __bf16* __restrict__ Kb,
                                                      const __bf16* __restrict__ Vt,
                                                      const float* __restrict__ mask,
                                                      int mask_half,
                                                      __bf16* __restrict__ att)
{
    __shared__ __align__(16) __bf16 KP[512 * 64];  // swizzled K [pos][64]; later swizzled P [64][512]
    __shared__ float msk[512];
    const int bh = blockIdx.x, b = bh >> 4, h = bh & 15;
    const int q0 = blockIdx.y * 64;
    const int t = threadIdx.x, l = t & 63, w = t >> 6;
    const int lrow = l & 15, lk = l >> 4;
    char* KPc = (char*)KP;

    // stage K: row pos = 128 B, 8 slots of 16 B, slot' = slot ^ (pos&7)
#pragma unroll
    for (int i = 0; i < 16; ++i) {
        int c = t + i * 256;
        int pos = c >> 3, slot = c & 7;
        *(i32x4*)(KPc + pos * 128 + ((slot ^ (pos & 7)) << 4)) =
            *(const i32x4*)(&Kb[((size_t)(b * 512 + pos)) * 1024 + h * 64 + slot * 8]);
    }
    for (int i = t; i < 512; i += 256) msk[i] = mask[b * 1024 + mask_half + i];

    // Q fragments (16 rows per wave)
    const int qrow = q0 + w * 16 + lrow;
    const __bf16* qptr = Q + ((size_t)(b * 512 + qrow)) * 1024 + h * 64;
    bf16x8 qf0 = *(const bf16x8*)(qptr + lk * 8);
    bf16x8 qf1 = *(const bf16x8*)(qptr + 32 + lk * 8);
    __syncthreads();

    const f32x4 zero = {0.f, 0.f, 0.f, 0.f};
    f32x4 sc[32];
#pragma unroll
    for (int j = 0; j < 32; ++j) {
        const char* kb = KPc + (j * 16 + lrow) * 128;
        bf16x8 k0 = *(const bf16x8*)(kb + ((lk ^ (lrow & 7)) << 4));
        bf16x8 k1 = *(const bf16x8*)(kb + (((lk + 4) ^ (lrow & 7)) << 4));
        f32x4 c = zero;
        c = MFMA16(qf0, k0, c);
        c = MFMA16(qf1, k1, c);
        sc[j] = c;
    }

    // softmax: lane owns col j*16+lrow, rows lk*4+r
    float mx[4] = {-3e38f, -3e38f, -3e38f, -3e38f};
#pragma unroll
    for (int j = 0; j < 32; ++j) {
        float mv = msk[j * 16 + lrow];
#pragma unroll
        for (int r = 0; r < 4; ++r) {
            float s = sc[j][r] * 0.125f;      // 1/sqrt(64)
            if (mv == 0.f) s = -1e9f;
            sc[j][r] = s;
            mx[r] = fmaxf(mx[r], s);
        }
    }
#pragma unroll
    for (int r = 0; r < 4; ++r)
        for (int d = 1; d < 16; d <<= 1) mx[r] = fmaxf(mx[r], __shfl_xor(mx[r], d));
    float sm[4] = {0.f, 0.f, 0.f, 0.f};
#pragma unroll
    for (int j = 0; j < 32; ++j)
#pragma unroll
        for (int r = 0; r < 4; ++r) {
            float e = __expf(sc[j][r] - mx[r]);
            sc[j][r] = e;
            sm[r] += e;
        }
#pragma unroll
    for (int r = 0; r < 4; ++r)
        for (int d = 1; d < 16; d <<= 1) sm[r] += __shfl_xor(sm[r], d);
    float inv[4];
#pragma unroll
    for (int r = 0; r < 4; ++r) inv[r] = 1.f / sm[r];

    __syncthreads();   // all waves done reading K -> reuse KP for P
    // P [64 rows][512 cols] bf16, row = 1024 B = 64 slots; slot' = slot ^ (row&7)
#pragma unroll
    for (int j = 0; j < 32; ++j) {
        int col = j * 16 + lrow;
        int slot = col >> 3, off = (col & 7) * 2;
#pragma unroll
        for (int r = 0; r < 4; ++r) {
            int row = w * 16 + lk * 4 + r;
            *(__bf16*)(KPc + row * 1024 + ((slot ^ (row & 7)) << 4) + off) = (__bf16)sc[j][r];
        }
    }
    __syncthreads();

    const __bf16* vsrc = Vt + (size_t)bh * 64 * 512;
    f32x4 av[4];
#pragma unroll
    for (int ni = 0; ni < 4; ++ni) av[ni] = zero;
#pragma unroll
    for (int ks = 0; ks < 16; ++ks) {
        int prow = w * 16 + lrow;
        bf16x8 pf = *(const bf16x8*)(KPc + prow * 1024 + (((ks * 4 + lk) ^ (lrow & 7)) << 4));
#pragma unroll
        for (int ni = 0; ni < 4; ++ni) {
            bf16x8 vf = *(const bf16x8*)(&vsrc[(ni * 16 + lrow) * 512 + ks * 32 + lk * 8]);
            av[ni] = MFMA16(pf, vf, av[ni]);
        }
    }
#pragma unroll
    for (int ni = 0; ni < 4; ++ni)
#pragma unroll
        for (int r = 0; r < 4; ++r) {
            int qq = q0 + w * 16 + lk * 4 + r;
            att[((size_t)(b * 512 + qq)) * 1024 + h * 64 + ni * 16 + lrow] =
                (__bf16)(av[ni][r] * inv[r]);
        }
}

// ---------------------------------------------------------------- layernorm (row of 1024)
__global__ __launch_bounds__(256) void ln_kernel(const float* __restrict__ X,
                                                 const float* __restrict__ g,
                                                 const float* __restrict__ bta,
                                                 __bf16* __restrict__ out)
{
    const int r = blockIdx.x, t = threadIdx.x;
    const float* x = X + (size_t)r * 1024;
    f32x4 v = *(const f32x4*)(x + t * 4);
    float s = v[0] + v[1] + v[2] + v[3];
    float q = v[0] * v[0] + v[1] * v[1] + v[2] * v[2] + v[3] * v[3];
#pragma unroll
    for (int d = 1; d < 64; d <<= 1) { s += __shfl_xor(s, d); q += __shfl_xor(q, d); }
    __shared__ float rs[4], rq[4];
    if ((t & 63) == 0) { rs[t >> 6] = s; rq[t >> 6] = q; }
    __syncthreads();
    s = rs[0] + rs[1] + rs[2] + rs[3];
    q = rq[0] + rq[1] + rq[2] + rq[3];
    float mu = s * (1.f / 1024.f);
    float var = q * (1.f / 1024.f) - mu * mu;
    float rstd = rsqrtf(var + 1e-5f);
#pragma unroll
    for (int j = 0; j < 4; ++j) {
        int c = t * 4 + j;
        out[(size_t)r * 1024 + c] = (__bf16)((v[j] - mu) * rstd * g[c] + bta[c]);
    }
}

// ---------------------------------------------------------------- pools
__global__ __launch_bounds__(256) void pool_f32_kernel(const float* __restrict__ X,
                                                       const float* __restrict__ mask,
                                                       int half, float* __restrict__ feats,
                                                       int off)
{
    const int b = blockIdx.y, d0 = blockIdx.x * 64;
    const int t = threadIdx.x, d = d0 + (t & 63), sl = t >> 6;
    float acc = 0.f, ms = 0.f;
#pragma unroll 4
    for (int s = sl * 128; s < sl * 128 + 128; ++s) {
        float m = mask[b * 1024 + half + s];
        acc += X[((size_t)b * 1024 + half + s) * 1024 + d] * m;
        ms += m;
    }
    __shared__ float ra[4][64];
    __shared__ float rm[4];
    ra[sl][t & 63] = acc;
    if ((t & 63) == 0) rm[sl] = ms;
    __syncthreads();
    if (t < 64) {
        float a = ra[0][t] + ra[1][t] + ra[2][t] + ra[3][t];
        float m = rm[0] + rm[1] + rm[2] + rm[3];
        feats[b * 4096 + off + d0 + t] = a / fmaxf(m, 1e-9f);
    }
}

__global__ __launch_bounds__(256) void pool_bf16_kernel(const __bf16* __restrict__ X,
                                                        const float* __restrict__ mask,
                                                        int half, float* __restrict__ feats,
                                                        int off)
{
    const int b = blockIdx.y, d0 = blockIdx.x * 64;
    const int t = threadIdx.x, d = d0 + (t & 63), sl = t >> 6;
    float acc = 0.f, ms = 0.f;
#pragma unroll 4
    for (int s = sl * 128; s < sl * 128 + 128; ++s) {
        float m = mask[b * 1024 + half + s];
        acc += (float)X[((size_t)b * 512 + s) * 1024 + d] * m;
        ms += m;
    }
    __shared__ float ra[4][64];
    __shared__ float rm[4];
    ra[sl][t & 63] = acc;
    if ((t & 63) == 0) rm[sl] = ms;
    __syncthreads();
    if (t < 64) {
        float a = ra[0][t] + ra[1][t] + ra[2][t] + ra[3][t];
        float m = rm[0] + rm[1] + rm[2] + rm[3];
        feats[b * 4096 + off + d0 + t] = a / fmaxf(m, 1e-9f);
    }
}

// ---------------------------------------------------------------- small fp32 MLP
__global__ __launch_bounds__(256) void fc_init_kernel(const float* __restrict__ b1,
                                                      const float* __restrict__ b2,
                                                      float* __restrict__ h1,
                                                      float* __restrict__ h2)
{
    int i = blockIdx.x * 256 + threadIdx.x;
    if (i < 16 * 1024) h1[i] = b1[i & 1023];
    else h2[i - 16 * 1024] = b2[(i - 16 * 1024) & 511];
}

template <int CH, int RELU_IN>
__global__ __launch_bounds__(256) void fc_atomic_kernel(const float* __restrict__ in,
                                                        const float* __restrict__ W,
                                                        float* __restrict__ out,
                                                        int IF, int OF)
{
    __shared__ float ins[16 * CH];
    const int t = threadIdx.x;
    const int col = blockIdx.x * 256 + t;
    const int i0 = blockIdx.y * CH;
#pragma unroll
    for (int idx = t; idx < 16 * CH; idx += 256) {
        int b = idx / CH, i = idx % CH;
        float v = in[b * IF + i0 + i];
        if (RELU_IN) v = fmaxf(v, 0.f);
        ins[idx] = v;
    }
    __syncthreads();
    float acc[16];
#pragma unroll
    for (int b = 0; b < 16; ++b) acc[b] = 0.f;
#pragma unroll 4
    for (int i = 0; i < CH; ++i) {
        float wv = W[(size_t)(i0 + i) * OF + col];
#pragma unroll
        for (int b = 0; b < 16; ++b) acc[b] += ins[b * CH + i] * wv;
    }
#pragma unroll
    for (int b = 0; b < 16; ++b) atomicAdd(out + b * OF + col, acc[b]);
}

__global__ __launch_bounds__(64) void mlp3_kernel(const float* __restrict__ h2,
                                                  const float* __restrict__ W3,
                                                  const float* __restrict__ b3,
                                                  float* __restrict__ out)
{
    int b = blockIdx.x, t = threadIdx.x;
    float a0 = 0.f, a1 = 0.f, a2 = 0.f;
    for (int i = t; i < 512; i += 64) {
        float hv = fmaxf(h2[b * 512 + i], 0.f);
        a0 += hv * W3[i * 3 + 0];
        a1 += hv * W3[i * 3 + 1];
        a2 += hv * W3[i * 3 + 2];
    }
#pragma unroll
    for (int d = 1; d < 64; d <<= 1) {
        a0 += __shfl_xor(a0, d);
        a1 += __shfl_xor(a1, d);
        a2 += __shfl_xor(a2, d);
    }
    if (t == 0) {
        out[b * 3 + 0] = a0 + b3[0];
        out[b * 3 + 1] = a1 + b3[1];
        out[b * 3 + 2] = a2 + b3[2];
    }
}

// ---------------------------------------------------------------- launch
extern "C" void kernel_launch(void* const* d_in, const int* in_sizes, int n_in,
                              void* d_out, int out_size, void* d_ws, size_t ws_size,
                              hipStream_t stream)
{
    const float* emb  = (const float*)d_in[0];
    const float* mask = (const float*)d_in[1];
    const float* W1 = (const float*)d_in[22];
    const float* b1 = (const float*)d_in[23];
    const float* W2 = (const float*)d_in[24];
    const float* b2 = (const float*)d_in[25];
    const float* W3 = (const float*)d_in[26];
    const float* b3 = (const float*)d_in[27];

    char* ws = (char*)d_ws;
    constexpr size_t MB = 1ull << 20;
    __bf16* Pb    = (__bf16*)(ws);                 // 16 MB (8192,1024) bf16
    __bf16* Hb    = (__bf16*)(ws + 16 * MB);       // 16 MB
    __bf16* Wt    = (__bf16*)(ws + 32 * MB);       // 16 MB: 8 x (1024,1024) bf16 W^T
    __bf16* Qb    = (__bf16*)(ws + 48 * MB);       // 16 MB
    __bf16* Kb    = (__bf16*)(ws + 64 * MB);       // 16 MB
    __bf16* Vt    = (__bf16*)(ws + 80 * MB);       // 16 MB (B,H,64,512)
    __bf16* attb  = (__bf16*)(ws + 96 * MB);       // 16 MB
    float*  Of    = (float*) (ws + 48 * MB);       // 32 MB, aliases Qb+Kb (dead by then)
    __bf16* ctx   = (__bf16*)(ws + 112 * MB);      // 16 MB
    float*  feats = (float*) (ws + 128 * MB);      // 256 KB (16,4096)
    float*  h1    = (float*) (ws + 128 * MB + 512 * 1024);  // 64 KB
    float*  h2    = (float*) (ws + 129 * MB);      // 32 KB

    cast_emb_kernel<<<8192, 256, 0, stream>>>(emb, Pb, Hb);
    const int widx[8] = {2, 4, 6, 8, 12, 14, 16, 18};   // p2h Wq,Wk,Wv,Wo then h2p
    for (int i = 0; i < 8; ++i)
        cast_wt_kernel<<<dim3(32, 32), dim3(32, 8), 0, stream>>>(
            (const float*)d_in[widx[i]], Wt + (size_t)i * 1024 * 1024);

    dim3 gg(8, 64);   // (N/128, M/128)
    for (int dir = 0; dir < 2; ++dir) {
        const __bf16* qin  = dir ? Hb : Pb;
        const __bf16* kvin = dir ? Pb : Hb;
        const int base = dir ? 12 : 2;
        const __bf16* wq = Wt + (size_t)(dir * 4 + 0) * 1048576;
        const __bf16* wk = Wt + (size_t)(dir * 4 + 1) * 1048576;
        const __bf16* wv = Wt + (size_t)(dir * 4 + 2) * 1048576;
        const __bf16* wo = Wt + (size_t)(dir * 4 + 3) * 1048576;
        const float* bq  = (const float*)d_in[base + 1];
        const float* bk  = (const float*)d_in[base + 3];
        const float* bv  = (const float*)d_in[base + 5];
        const float* bo  = (const float*)d_in[base + 7];
        const float* lng = (const float*)d_in[base + 8];
        const float* lnb = (const float*)d_in[base + 9];
        const int kvhalf  = dir ? 0 : 512;    // p2h attends hypothesis (mask half 512)
        const int reshalf = dir ? 512 : 0;    // residual = q_in slice of embedded

        gemm_bt<0><<<gg, 256, 0, stream>>>(qin,  wq, bq, Qb, nullptr, nullptr, 0, 8192, 1024, 1024);
        gemm_bt<0><<<gg, 256, 0, stream>>>(kvin, wk, bk, Kb, nullptr, nullptr, 0, 8192, 1024, 1024);
        gemm_bt<1><<<gg, 256, 0, stream>>>(kvin, wv, bv, Vt, nullptr, nullptr, 0, 8192, 1024, 1024);
        attn_kernel<<<dim3(256, 8), 256, 0, stream>>>(Qb, Kb, Vt, mask, kvhalf, attb);
        gemm_bt<2><<<gg, 256, 0, stream>>>(attb, wo, bo, nullptr, Of, emb, reshalf, 8192, 1024, 1024);
        ln_kernel<<<8192, 256, 0, stream>>>(Of, lng, lnb, ctx);
        pool_bf16_kernel<<<dim3(16, 16), 256, 0, stream>>>(ctx, mask, dir ? 512 : 0,
                                                           feats, 2048 + dir * 1024);
    }
    pool_f32_kernel<<<dim3(16, 16), 256, 0, stream>>>(emb, mask, 0,   feats, 0);
    pool_f32_kernel<<<dim3(16, 16), 256, 0, stream>>>(emb, mask, 512, feats, 1024);

    fc_init_kernel<<<96, 256, 0, stream>>>(b1, b2, h1, h2);
    fc_atomic_kernel<128, 0><<<dim3(4, 32), 256, 0, stream>>>(feats, W1, h1, 4096, 1024);
    fc_atomic_kernel<32, 1><<<dim3(2, 32), 256, 0, stream>>>(h1, W2, h2, 1024, 512);
    mlp3_kernel<<<16, 64, 0, stream>>>(h2, W3, b3, (float*)d_out);
}

// Round 4
// 580.300 us; speedup vs baseline: 1.3841x; 1.0741x over previous
//
#include <hip/hip_runtime.h>
#include <hip/hip_bf16.h>

typedef __attribute__((ext_vector_type(8))) __bf16 bf16x8;
typedef __attribute__((ext_vector_type(4))) float f32x4;
typedef __attribute__((ext_vector_type(4))) int i32x4;
typedef __attribute__((ext_vector_type(4))) unsigned short u16x4;

#define MFMA16(a, b, c) __builtin_amdgcn_mfma_f32_16x16x32_bf16((a), (b), (c), 0, 0, 0)

__device__ __forceinline__ void gload_lds16(const void* g, void* l)
{
    __builtin_amdgcn_global_load_lds(
        (const __attribute__((address_space(1))) unsigned int*)g,
        (__attribute__((address_space(3))) unsigned int*)l, 16, 0, 0);
}

// ---------------------------------------------------------------- casts
// embedded (B,1024,1024) fp32 -> premise/hypothesis (8192,1024) bf16 contiguous
__global__ __launch_bounds__(256) void cast_emb_kernel(const float* __restrict__ emb,
                                                       __bf16* __restrict__ Pb,
                                                       __bf16* __restrict__ Hb)
{
    int i = (blockIdx.x * 256 + threadIdx.x) * 4;   // element in (8192,1024) dest space
    int r = i >> 10, d = i & 1023;
    size_t src = ((size_t)(r >> 9) * 1024 + (r & 511)) * 1024 + d;
    f32x4 p = *(const f32x4*)(emb + src);
    f32x4 h = *(const f32x4*)(emb + src + 512 * 1024);
    union { __bf16 b[4]; u16x4 u; } cp, ch;
#pragma unroll
    for (int j = 0; j < 4; ++j) { cp.b[j] = (__bf16)p[j]; ch.b[j] = (__bf16)h[j]; }
    *(u16x4*)(Pb + i) = cp.u;
    *(u16x4*)(Hb + i) = ch.u;
}

// 8 weights W (1024,1024) fp32 row-major -> Wt (1024,1024) bf16, Wt[n][k] = W[k][n]
struct WPtrs { const float* p[8]; };
__global__ __launch_bounds__(256) void cast_wt_kernel(WPtrs wp, __bf16* __restrict__ Wt0)
{
    const float* W = wp.p[blockIdx.z];
    __bf16* Wt = Wt0 + (size_t)blockIdx.z * 1048576;
    __shared__ float tile[32][33];
    int n0 = blockIdx.x * 32, k0 = blockIdx.y * 32;
    int tx = threadIdx.x, ty = threadIdx.y;
#pragma unroll
    for (int i = ty; i < 32; i += 8)
        tile[i][tx] = W[(size_t)(k0 + i) * 1024 + n0 + tx];
    __syncthreads();
#pragma unroll
    for (int i = ty; i < 32; i += 8)
        Wt[(size_t)(n0 + i) * 1024 + k0 + tx] = (__bf16)tile[tx][i];
}

// ---------------------------------------------------------------- GEMM (m97 structure)
// C(M,N) = A(M,K) @ Bt^T + bias.  A,Bt bf16 row-major, Bt is (N,K).
// EPI 0: Cb[row*N+col] = bf16(v)
// EPI 2: Cf[row*N+col] = v + resid  (fp32, resid = embedded slice)
// EPI 3: N=2048 fused K|V: col<1024 -> Cb[row*1024+col] (K, bias);
//        col>=1024 -> Cb2 V-transpose (B,H,64,512), bias2
template <int EPI>
__global__ __launch_bounds__(256, 3) void gemm_bt(const __bf16* __restrict__ A,
                                                  const __bf16* __restrict__ Bt,
                                                  const float* __restrict__ bias,
                                                  const float* __restrict__ bias2,
                                                  __bf16* __restrict__ Cb,
                                                  __bf16* __restrict__ Cb2,
                                                  float* __restrict__ Cf,
                                                  const float* __restrict__ resid,
                                                  int resid_half, int M, int N, int K)
{
    __shared__ __align__(16) __bf16 As[128 * 32];
    __shared__ __align__(16) __bf16 Bs[128 * 32];
    const int t = threadIdx.x;
    const int l = t & 63, w = t >> 6;
    const int wr = w >> 1, wc = w & 1;
    const int lrow = l & 15, lk = l >> 4;
    const int m0 = blockIdx.y * 128, n0 = blockIdx.x * 128;
    const int r0 = t >> 2, kc0 = (t & 3) * 8;

    const __bf16* gA0 = A + (size_t)(m0 + r0) * K + kc0;
    const __bf16* gA1 = gA0 + (size_t)64 * K;
    const __bf16* gB0 = Bt + (size_t)(n0 + r0) * K + kc0;
    const __bf16* gB1 = gB0 + (size_t)64 * K;
    // LDS dests are lane-linear (byte offset == t*16) -> valid global_load_lds targets
    __bf16* dA0 = &As[r0 * 32 + kc0];
    __bf16* dA1 = &As[(r0 + 64) * 32 + kc0];
    __bf16* dB0 = &Bs[r0 * 32 + kc0];
    __bf16* dB1 = &Bs[(r0 + 64) * 32 + kc0];

    const f32x4 zero = {0.f, 0.f, 0.f, 0.f};
    f32x4 acc[4][4];
#pragma unroll
    for (int mi = 0; mi < 4; ++mi)
#pragma unroll
        for (int ni = 0; ni < 4; ++ni) acc[mi][ni] = zero;

    const int nk = K >> 5;
    for (int kt = 0; kt < nk; ++kt) {
        const int ko = kt * 32;
        gload_lds16(gA0 + ko, dA0);
        gload_lds16(gA1 + ko, dA1);
        gload_lds16(gB0 + ko, dB0);
        gload_lds16(gB1 + ko, dB1);
        __syncthreads();   // vmcnt(0) drain before barrier -> LDS ready
        bf16x8 af[4], bfv[4];
#pragma unroll
        for (int mi = 0; mi < 4; ++mi)
            af[mi] = *(const bf16x8*)(&As[(wr * 64 + mi * 16 + lrow) * 32 + lk * 8]);
#pragma unroll
        for (int ni = 0; ni < 4; ++ni)
            bfv[ni] = *(const bf16x8*)(&Bs[(wc * 64 + ni * 16 + lrow) * 32 + lk * 8]);
#pragma unroll
        for (int mi = 0; mi < 4; ++mi)
#pragma unroll
            for (int ni = 0; ni < 4; ++ni)
                acc[mi][ni] = MFMA16(af[mi], bfv[ni], acc[mi][ni]);
        __syncthreads();
    }

#pragma unroll
    for (int mi = 0; mi < 4; ++mi) {
#pragma unroll
        for (int ni = 0; ni < 4; ++ni) {
            int col = n0 + wc * 64 + ni * 16 + lrow;
            float bv = (EPI == 3 && col >= 1024) ? bias2[col - 1024] : bias[col];
#pragma unroll
            for (int r = 0; r < 4; ++r) {
                int row = m0 + wr * 64 + mi * 16 + lk * 4 + r;
                float v = acc[mi][ni][r] + bv;
                if (EPI == 0) {
                    Cb[(size_t)row * N + col] = (__bf16)v;
                } else if (EPI == 3) {
                    if (col < 1024) {
                        Cb[(size_t)row * 1024 + col] = (__bf16)v;
                    } else {
                        int c2 = col - 1024;
                        int b_ = row >> 9, pos = row & 511;
                        int h_ = c2 >> 6, hd = c2 & 63;
                        Cb2[(((size_t)(b_ * 16 + h_) * 64 + hd) << 9) + pos] = (__bf16)v;
                    }
                } else {
                    int b_ = row >> 9, s = row & 511;
                    float rv = resid[((size_t)b_ * 1024 + resid_half + s) * 1024 + col];
                    Cf[(size_t)row * N + col] = v + rv;
                }
            }
        }
    }
}

// ---------------------------------------------------------------- attention
// One WG per (bh, 64-row Q block). K staged swizzled in LDS (reused as P);
// V read directly from global (L2-resident, 8 WGs/bh share an XCD).
// Swapped QK^T (mfma(K,Q)): lane holds P[k=j*16+lk*4+r][q=w*16+lrow] -> scalar softmax,
// 2-step shfl reduce, packed b64 P writes, wave-private P rows (no extra barrier).
__global__ __launch_bounds__(256, 2) void attn_kernel(const __bf16* __restrict__ Q,
                                                      const __bf16* __restrict__ Kb,
                                                      const __bf16* __restrict__ Vt,
                                                      const float* __restrict__ mask,
                                                      int mask_half,
                                                      __bf16* __restrict__ att)
{
    __shared__ __align__(16) __bf16 KP[512 * 64];  // swizzled K [pos][64d]; later swizzled P [64q][512k]
    __shared__ __align__(16) float msk[512];
    const int bh = blockIdx.x, b = bh >> 4, h = bh & 15;
    const int q0 = blockIdx.y * 64;
    const int t = threadIdx.x, l = t & 63, w = t >> 6;
    const int lrow = l & 15, lk = l >> 4;
    char* KPc = (char*)KP;

    // stage K: row pos = 128 B, 8 slots of 16 B, slot' = slot ^ (pos&7)
#pragma unroll
    for (int i = 0; i < 16; ++i) {
        int c = t + i * 256;
        int pos = c >> 3, slot = c & 7;
        *(i32x4*)(KPc + pos * 128 + ((slot ^ (pos & 7)) << 4)) =
            *(const i32x4*)(&Kb[((size_t)(b * 512 + pos)) * 1024 + h * 64 + slot * 8]);
    }
    for (int i = t; i < 512; i += 256) msk[i] = mask[b * 1024 + mask_half + i];

    // Q fragments: lane reads Q row (q0+w*16+lrow), d = lk*8.. ; serves as B-operand of mfma(K,Q)
    const int qrow = q0 + w * 16 + lrow;
    const __bf16* qptr = Q + ((size_t)(b * 512 + qrow)) * 1024 + h * 64;
    bf16x8 qf0 = *(const bf16x8*)(qptr + lk * 8);
    bf16x8 qf1 = *(const bf16x8*)(qptr + 32 + lk * 8);
    __syncthreads();

    const f32x4 zero = {0.f, 0.f, 0.f, 0.f};
    f32x4 sc[32];
#pragma unroll
    for (int j = 0; j < 32; ++j) {
        const char* kb = KPc + (j * 16 + lrow) * 128;      // A-frag: K row = j*16+lrow
        bf16x8 k0 = *(const bf16x8*)(kb + ((lk ^ (lrow & 7)) << 4));
        bf16x8 k1 = *(const bf16x8*)(kb + (((lk + 4) ^ (lrow & 7)) << 4));
        f32x4 c = zero;
        c = MFMA16(k0, qf0, c);    // swapped: C[row=k local][col=q local]
        c = MFMA16(k1, qf1, c);
        sc[j] = c;
    }

    // softmax: lane owns q = w*16+lrow, k = j*16 + lk*4 + r  -> scalar reduce over lk lanes
    float mx = -3e38f;
#pragma unroll
    for (int j = 0; j < 32; ++j) {
        f32x4 mv = *(const f32x4*)(&msk[j * 16 + lk * 4]);
#pragma unroll
        for (int r = 0; r < 4; ++r) {
            float s = sc[j][r] * 0.125f;      // 1/sqrt(64)
            if (mv[r] == 0.f) s = -1e9f;
            sc[j][r] = s;
            mx = fmaxf(mx, s);
        }
    }
    mx = fmaxf(mx, __shfl_xor(mx, 16));
    mx = fmaxf(mx, __shfl_xor(mx, 32));
    float sm = 0.f;
#pragma unroll
    for (int j = 0; j < 32; ++j)
#pragma unroll
        for (int r = 0; r < 4; ++r) {
            float e = __expf(sc[j][r] - mx);
            sc[j][r] = e;
            sm += e;
        }
    sm += __shfl_xor(sm, 16);
    sm += __shfl_xor(sm, 32);
    const float inv = 1.f / sm;

    __syncthreads();   // all waves done reading K -> reuse KP for P
    // P [64 q][512 k] bf16 (normalized); row = 1024 B; swizzle 16B slots by q&7.
    // Each wave writes only its own 16 q rows -> wave-private, no barrier before PV.
    const int prow = w * 16 + lrow;
    char* prowp = KPc + prow * 1024;
    const int psw = (prow & 7);
#pragma unroll
    for (int j = 0; j < 32; ++j) {
        union { __bf16 b[4]; unsigned long long u; } pk;
#pragma unroll
        for (int r = 0; r < 4; ++r) pk.b[r] = (__bf16)(sc[j][r] * inv);
        int slot = j * 2 + (lk >> 1);
        *(unsigned long long*)(prowp + (((slot ^ psw) << 4) | ((lk & 1) * 8))) = pk.u;
    }

    const __bf16* vsrc = Vt + (size_t)bh * 64 * 512;
    f32x4 av[4];
#pragma unroll
    for (int ni = 0; ni < 4; ++ni) av[ni] = zero;
#pragma unroll
    for (int ks = 0; ks < 16; ++ks) {
        bf16x8 pf = *(const bf16x8*)(prowp + (((ks * 4 + lk) ^ psw) << 4));
#pragma unroll
        for (int ni = 0; ni < 4; ++ni) {
            bf16x8 vf = *(const bf16x8*)(&vsrc[(ni * 16 + lrow) * 512 + ks * 32 + lk * 8]);
            av[ni] = MFMA16(pf, vf, av[ni]);
        }
    }
#pragma unroll
    for (int ni = 0; ni < 4; ++ni)
#pragma unroll
        for (int r = 0; r < 4; ++r) {
            int qq = q0 + w * 16 + lk * 4 + r;
            att[((size_t)(b * 512 + qq)) * 1024 + h * 64 + ni * 16 + lrow] =
                (__bf16)av[ni][r];
        }
}

// ---------------------------------------------------------------- layernorm (row of 1024)
__global__ __launch_bounds__(256) void ln_kernel(const float* __restrict__ X,
                                                 const float* __restrict__ g,
                                                 const float* __restrict__ bta,
                                                 __bf16* __restrict__ out)
{
    const int r = blockIdx.x, t = threadIdx.x;
    const float* x = X + (size_t)r * 1024;
    f32x4 v = *(const f32x4*)(x + t * 4);
    float s = v[0] + v[1] + v[2] + v[3];
    float q = v[0] * v[0] + v[1] * v[1] + v[2] * v[2] + v[3] * v[3];
#pragma unroll
    for (int d = 1; d < 64; d <<= 1) { s += __shfl_xor(s, d); q += __shfl_xor(q, d); }
    __shared__ float rs[4], rq[4];
    if ((t & 63) == 0) { rs[t >> 6] = s; rq[t >> 6] = q; }
    __syncthreads();
    s = rs[0] + rs[1] + rs[2] + rs[3];
    q = rq[0] + rq[1] + rq[2] + rq[3];
    float mu = s * (1.f / 1024.f);
    float var = q * (1.f / 1024.f) - mu * mu;
    float rstd = rsqrtf(var + 1e-5f);
#pragma unroll
    for (int j = 0; j < 4; ++j) {
        int c = t * 4 + j;
        out[(size_t)r * 1024 + c] = (__bf16)((v[j] - mu) * rstd * g[c] + bta[c]);
    }
}

// ---------------------------------------------------------------- pools
// z selects half: emb rows [z*512, z*512+512) -> feats[b][z*1024 + d]
__global__ __launch_bounds__(256) void pool_f32_kernel(const float* __restrict__ X,
                                                       const float* __restrict__ mask,
                                                       float* __restrict__ feats)
{
    const int b = blockIdx.y, d0 = blockIdx.x * 64, half = blockIdx.z * 512;
    const int t = threadIdx.x, d = d0 + (t & 63), sl = t >> 6;
    float acc = 0.f, ms = 0.f;
#pragma unroll 4
    for (int s = sl * 128; s < sl * 128 + 128; ++s) {
        float m = mask[b * 1024 + half + s];
        acc += X[((size_t)b * 1024 + half + s) * 1024 + d] * m;
        ms += m;
    }
    __shared__ float ra[4][64];
    __shared__ float rm[4];
    ra[sl][t & 63] = acc;
    if ((t & 63) == 0) rm[sl] = ms;
    __syncthreads();
    if (t < 64) {
        float a = ra[0][t] + ra[1][t] + ra[2][t] + ra[3][t];
        float m = rm[0] + rm[1] + rm[2] + rm[3];
        feats[b * 4096 + blockIdx.z * 1024 + d0 + t] = a / fmaxf(m, 1e-9f);
    }
}

__global__ __launch_bounds__(256) void pool_bf16_kernel(const __bf16* __restrict__ X,
                                                        const float* __restrict__ mask,
                                                        int half, float* __restrict__ feats,
                                                        int off)
{
    const int b = blockIdx.y, d0 = blockIdx.x * 64;
    const int t = threadIdx.x, d = d0 + (t & 63), sl = t >> 6;
    float acc = 0.f, ms = 0.f;
#pragma unroll 4
    for (int s = sl * 128; s < sl * 128 + 128; ++s) {
        float m = mask[b * 1024 + half + s];
        acc += (float)X[((size_t)b * 512 + s) * 1024 + d] * m;
        ms += m;
    }
    __shared__ float ra[4][64];
    __shared__ float rm[4];
    ra[sl][t & 63] = acc;
    if ((t & 63) == 0) rm[sl] = ms;
    __syncthreads();
    if (t < 64) {
        float a = ra[0][t] + ra[1][t] + ra[2][t] + ra[3][t];
        float m = rm[0] + rm[1] + rm[2] + rm[3];
        feats[b * 4096 + off + d0 + t] = a / fmaxf(m, 1e-9f);
    }
}

// ---------------------------------------------------------------- small fp32 MLP
__global__ __launch_bounds__(256) void fc_init_kernel(const float* __restrict__ b1,
                                                      const float* __restrict__ b2,
                                                      float* __restrict__ h1,
                                                      float* __restrict__ h2)
{
    int i = blockIdx.x * 256 + threadIdx.x;
    if (i < 16 * 1024) h1[i] = b1[i & 1023];
    else h2[i - 16 * 1024] = b2[(i - 16 * 1024) & 511];
}

template <int CH, int RELU_IN>
__global__ __launch_bounds__(256) void fc_atomic_kernel(const float* __restrict__ in,
                                                        const float* __restrict__ W,
                                                        float* __restrict__ out,
                                                        int IF, int OF)
{
    __shared__ float ins[16 * CH];
    const int t = threadIdx.x;
    const int col = blockIdx.x * 256 + t;
    const int i0 = blockIdx.y * CH;
#pragma unroll
    for (int idx = t; idx < 16 * CH; idx += 256) {
        int b = idx / CH, i = idx % CH;
        float v = in[b * IF + i0 + i];
        if (RELU_IN) v = fmaxf(v, 0.f);
        ins[idx] = v;
    }
    __syncthreads();
    float acc[16];
#pragma unroll
    for (int b = 0; b < 16; ++b) acc[b] = 0.f;
#pragma unroll 4
    for (int i = 0; i < CH; ++i) {
        float wv = W[(size_t)(i0 + i) * OF + col];
#pragma unroll
        for (int b = 0; b < 16; ++b) acc[b] += ins[b * CH + i] * wv;
    }
#pragma unroll
    for (int b = 0; b < 16; ++b) atomicAdd(out + b * OF + col, acc[b]);
}

__global__ __launch_bounds__(64) void mlp3_kernel(const float* __restrict__ h2,
                                                  const float* __restrict__ W3,
                                                  const float* __restrict__ b3,
                                                  float* __restrict__ out)
{
    int b = blockIdx.x, t = threadIdx.x;
    float a0 = 0.f, a1 = 0.f, a2 = 0.f;
    for (int i = t; i < 512; i += 64) {
        float hv = fmaxf(h2[b * 512 + i], 0.f);
        a0 += hv * W3[i * 3 + 0];
        a1 += hv * W3[i * 3 + 1];
        a2 += hv * W3[i * 3 + 2];
    }
#pragma unroll
    for (int d = 1; d < 64; d <<= 1) {
        a0 += __shfl_xor(a0, d);
        a1 += __shfl_xor(a1, d);
        a2 += __shfl_xor(a2, d);
    }
    if (t == 0) {
        out[b * 3 + 0] = a0 + b3[0];
        out[b * 3 + 1] = a1 + b3[1];
        out[b * 3 + 2] = a2 + b3[2];
    }
}

// ---------------------------------------------------------------- launch
extern "C" void kernel_launch(void* const* d_in, const int* in_sizes, int n_in,
                              void* d_out, int out_size, void* d_ws, size_t ws_size,
                              hipStream_t stream)
{
    const float* emb  = (const float*)d_in[0];
    const float* mask = (const float*)d_in[1];
    const float* W1 = (const float*)d_in[22];
    const float* b1 = (const float*)d_in[23];
    const float* W2 = (const float*)d_in[24];
    const float* b2 = (const float*)d_in[25];
    const float* W3 = (const float*)d_in[26];
    const float* b3 = (const float*)d_in[27];

    char* ws = (char*)d_ws;
    constexpr size_t MB = 1ull << 20;
    __bf16* Pb    = (__bf16*)(ws);                 // 16 MB (8192,1024) bf16
    __bf16* Hb    = (__bf16*)(ws + 16 * MB);       // 16 MB
    __bf16* Wt    = (__bf16*)(ws + 32 * MB);       // 16 MB: 8 x (1024,1024) bf16 W^T
    __bf16* Qb    = (__bf16*)(ws + 48 * MB);       // 16 MB
    __bf16* Kb    = (__bf16*)(ws + 64 * MB);       // 16 MB
    __bf16* Vt    = (__bf16*)(ws + 80 * MB);       // 16 MB (B,H,64,512)
    __bf16* attb  = (__bf16*)(ws + 96 * MB);       // 16 MB
    float*  Of    = (float*) (ws + 48 * MB);       // 32 MB, aliases Qb+Kb (dead by then)
    __bf16* ctx   = (__bf16*)(ws + 112 * MB);      // 16 MB
    float*  feats = (float*) (ws + 128 * MB);      // 256 KB (16,4096)
    float*  h1    = (float*) (ws + 128 * MB + 512 * 1024);  // 64 KB
    float*  h2    = (float*) (ws + 129 * MB);      // 32 KB

    cast_emb_kernel<<<8192, 256, 0, stream>>>(emb, Pb, Hb);
    WPtrs wp;
    const int widx[8] = {2, 4, 6, 8, 12, 14, 16, 18};   // p2h Wq,Wk,Wv,Wo then h2p
    for (int i = 0; i < 8; ++i) wp.p[i] = (const float*)d_in[widx[i]];
    cast_wt_kernel<<<dim3(32, 32, 8), dim3(32, 8), 0, stream>>>(wp, Wt);

    dim3 gg(8, 64);     // (N/128, M/128) for N=1024
    dim3 gkv(16, 64);   // N=2048 fused K|V
    for (int dir = 0; dir < 2; ++dir) {
        const __bf16* qin  = dir ? Hb : Pb;
        const __bf16* kvin = dir ? Pb : Hb;
        const int base = dir ? 12 : 2;
        const __bf16* wq  = Wt + (size_t)(dir * 4 + 0) * 1048576;
        const __bf16* wkv = Wt + (size_t)(dir * 4 + 1) * 1048576;  // Wk|Wv contiguous
        const __bf16* wo  = Wt + (size_t)(dir * 4 + 3) * 1048576;
        const float* bq  = (const float*)d_in[base + 1];
        const float* bk  = (const float*)d_in[base + 3];
        const float* bv  = (const float*)d_in[base + 5];
        const float* bo  = (const float*)d_in[base + 7];
        const float* lng = (const float*)d_in[base + 8];
        const float* lnb = (const float*)d_in[base + 9];
        const int kvhalf  = dir ? 0 : 512;    // p2h attends hypothesis (mask half 512)
        const int reshalf = dir ? 512 : 0;    // residual = q_in slice of embedded

        gemm_bt<0><<<gg, 256, 0, stream>>>(qin, wq, bq, nullptr, Qb, nullptr,
                                           nullptr, nullptr, 0, 8192, 1024, 1024);
        gemm_bt<3><<<gkv, 256, 0, stream>>>(kvin, wkv, bk, bv, Kb, Vt,
                                            nullptr, nullptr, 0, 8192, 2048, 1024);
        attn_kernel<<<dim3(256, 8), 256, 0, stream>>>(Qb, Kb, Vt, mask, kvhalf, attb);
        gemm_bt<2><<<gg, 256, 0, stream>>>(attb, wo, bo, nullptr, nullptr, nullptr,
                                           Of, emb, reshalf, 8192, 1024, 1024);
        ln_kernel<<<8192, 256, 0, stream>>>(Of, lng, lnb, ctx);
        pool_bf16_kernel<<<dim3(16, 16), 256, 0, stream>>>(ctx, mask, dir ? 512 : 0,
                                                           feats, 2048 + dir * 1024);
    }
    pool_f32_kernel<<<dim3(16, 16, 2), 256, 0, stream>>>(emb, mask, feats);

    fc_init_kernel<<<96, 256, 0, stream>>>(b1, b2, h1, h2);
    fc_atomic_kernel<128, 0><<<dim3(4, 32), 256, 0, stream>>>(feats, W1, h1, 4096, 1024);
    fc_atomic_kernel<32, 1><<<dim3(2, 32), 256, 0, stream>>>(h1, W2, h2, 1024, 512);
    mlp3_kernel<<<16, 64, 0, stream>>>(h2, W3, b3, (float*)d_out);
}